// Round 3
// baseline (383.038 us; speedup 1.0000x reference)
//
#include <hip/hip_runtime.h>
#include <stdint.h>

// Problem constants
#define BATCH  8
#define CH     256
#define HH     96
#define WW     96
#define NHEADS 8
#define HD     32
#define KS     7
#define HWP    (HH*WW)          // 9216 pixels per image
#define SCALE  0.17677669529663687f   // 1/sqrt(32)

// attention kernel geometry
#define HSTR  24     // halo row stride in pixels (mult of 8 -> 16B-aligned rows)
#define HSLOT 576    // staged halo slots = 24 rows * 24 stride
#define NT    11     // QK n-tiles of 16 over 176 padded dense keys
#define PBS   200    // Pbuf row stride (ushorts); 400B -> 2-way banks, 16B aligned

typedef unsigned short ushort_t;
typedef unsigned short us8 __attribute__((ext_vector_type(8)));
typedef short s8v __attribute__((ext_vector_type(8)));   // MFMA A/B frag (8 bf16)
typedef float f4v __attribute__((ext_vector_type(4)));   // MFMA C/D frag

__device__ __forceinline__ ushort_t f2bf(float f){
  unsigned int u = __float_as_uint(f);
  u = u + 0x7fffu + ((u >> 16) & 1u);
  return (ushort_t)(u >> 16);
}
__device__ __forceinline__ float bflo(unsigned int u){ return __uint_as_float(u << 16); }

__device__ __forceinline__ void gload_lds16(const void* g, void* l){
  __builtin_amdgcn_global_load_lds(
      (const __attribute__((address_space(1))) void*)g,
      (__attribute__((address_space(3))) void*)l, 16, 0, 0);
}

// ---------------------------------------------------------------- kernel 1
__global__ __launch_bounds__(256) void wcvt_kernel(
    const float* __restrict__ wq, const float* __restrict__ wk,
    const float* __restrict__ wv, const float* __restrict__ wp,
    ushort_t* __restrict__ wbf)
{
  int i = blockIdx.x*256 + threadIdx.x;
  int mat = i >> 16;
  int off = i & 65535;
  const float* src = (mat==0) ? wq : (mat==1) ? wk : (mat==2) ? wv : wp;
  wbf[i] = f2bf(src[off]);
}

// ---------------------------------------------------------------- kernel 2
// x (B,C,H,W) fp32 -> xT (B, HW, C) bf16
__global__ __launch_bounds__(256) void xpose_kernel(
    const float* __restrict__ x, ushort_t* __restrict__ xT)
{
  __shared__ unsigned int tile[32][33];
  int p0 = blockIdx.x * 64;
  int c0 = blockIdx.y * 32;
  int b  = blockIdx.z;
  int tid = threadIdx.x;
  int tx = tid & 31, ty = tid >> 5;
  const float* xb = x + ((size_t)(b*CH + c0))*HWP;
  #pragma unroll
  for (int r = 0; r < 4; r++){
    int c = r*8 + ty;
    float2 v = *(const float2*)(xb + (size_t)c*HWP + p0 + tx*2);
    tile[c][tx] = (unsigned int)f2bf(v.x) | ((unsigned int)f2bf(v.y) << 16);
  }
  __syncthreads();
  int pv = tid >> 2, cq = tid & 3;
  ushort_t tmp[8];
  #pragma unroll
  for (int s = 0; s < 8; s++){
    unsigned int w = tile[cq*8 + s][pv >> 1];
    tmp[s] = (ushort_t)((pv & 1) ? (w >> 16) : (w & 0xffffu));
  }
  *(us8*)(xT + ((size_t)(b*HWP + p0 + pv))*CH + c0 + cq*8) = *(us8*)tmp;
}

// ---------------------------------------------------------------- kernel 3
// QKV GEMM: m97 structure; writes q(prescaled)/k/v as [b][head][pix][hd] bf16
__global__ __launch_bounds__(256) void qkv_gemm(
    const ushort_t* __restrict__ xT, const ushort_t* __restrict__ wbf,
    ushort_t* __restrict__ qb, ushort_t* __restrict__ kb, ushort_t* __restrict__ vb)
{
  __shared__ ushort_t As[128*32];
  __shared__ ushort_t Bs[128*32];
  int m0 = blockIdx.x * 128;
  int n0 = blockIdx.y * 128;
  int b  = blockIdx.z / 3;
  int mat= blockIdx.z % 3;
  int tid = threadIdx.x;
  int wave = tid >> 6, lane = tid & 63;
  const ushort_t* Abase = xT + ((size_t)(b*HWP + m0))*CH;
  const ushort_t* Bbase = wbf + mat*65536 + n0*CH;

  f4v acc[4][4];
  #pragma unroll
  for (int i=0;i<4;i++)
    #pragma unroll
    for (int j=0;j<4;j++) acc[i][j] = (f4v){0.f,0.f,0.f,0.f};

  int wm = wave & 1, wn = wave >> 1;
  int lane16 = lane & 15, quad = lane >> 4;
  int lrow = lane >> 2, lchunk = lane & 3;

  for (int kt = 0; kt < 8; kt++){
    #pragma unroll
    for (int inst = 0; inst < 2; inst++){
      int row0 = wave*32 + inst*16;
      gload_lds16(Abase + (size_t)(row0 + lrow)*CH + kt*32 + lchunk*8, &As[row0*32]);
      gload_lds16(Bbase + (size_t)(row0 + lrow)*CH + kt*32 + lchunk*8, &Bs[row0*32]);
    }
    __syncthreads();
    s8v a[4], bf[4];
    #pragma unroll
    for (int mi=0;mi<4;mi++) a[mi]  = *(const s8v*)&As[(wm*64 + mi*16 + lane16)*32 + quad*8];
    #pragma unroll
    for (int ni=0;ni<4;ni++) bf[ni] = *(const s8v*)&Bs[(wn*64 + ni*16 + lane16)*32 + quad*8];
    #pragma unroll
    for (int mi=0;mi<4;mi++)
      #pragma unroll
      for (int ni=0;ni<4;ni++)
        acc[mi][ni] = __builtin_amdgcn_mfma_f32_16x16x32_bf16(a[mi], bf[ni], acc[mi][ni], 0, 0, 0);
    __syncthreads();
  }

  ushort_t* dst = (mat==0) ? qb : (mat==1) ? kb : vb;
  float sc = (mat==0) ? SCALE : 1.0f;
  size_t obase = (size_t)b * NHEADS * HWP * HD;
  #pragma unroll
  for (int mi=0;mi<4;mi++){
    #pragma unroll
    for (int ni=0;ni<4;ni++){
      int o = n0 + wn*64 + ni*16 + lane16;
      int head = o >> 5, hd = o & 31;
      #pragma unroll
      for (int r=0;r<4;r++){
        int m = m0 + wm*64 + mi*16 + quad*4 + r;
        dst[obase + ((size_t)head*HWP + m)*HD + hd] = f2bf(acc[mi][ni][r] * sc);
      }
    }
  }
}

// ---------------------------------------------------------------- kernel 4
// MFMA neighborhood attention. Block = 16x16 query tile for one (b, head).
// Per query-row (16 queries): dense keys = 7 halo rows x 24-stride = 176 padded.
//  QK:  logits^T = K * Q^T  -> 11 mfma_16x16x32 (k = hd = 32, one step)
//       C-layout: row = key-in-tile (quad*4+reg), col = query (lane16)
//  softmax in-layout (query = lane16): masked bias add, exp (logits tiny, no
//       max needed), row-sum = 2 shuffles (xor 16/32). P normalized, bf16.
//  P -> Pbuf[query][key] via ds_write_b64 (4 consecutive keys per lane).
//  AV:  out = P * V -> 12 mfma (6 k-steps x 2 ch-tiles); V staged TRANSPOSED
//       vTT[ch][pix] so B-frags are 16B contiguous.
// LDS ~98 KB -> 1 block/CU; no barrier after staging (P round-trip same-wave).
__global__ __launch_bounds__(256) void attn_kernel(
    const ushort_t* __restrict__ qb, const ushort_t* __restrict__ kb,
    const ushort_t* __restrict__ vb, const float* __restrict__ rpb,
    ushort_t* __restrict__ merged)
{
  __shared__ ushort_t kT[4*HSLOT*8];     // 36864 B  [chunk][pix][8]
  __shared__ ushort_t vTT[32*HSLOT];     // 36864 B  [ch][pix]
  __shared__ ushort_t Pbuf[4][16*PBS];   // 25600 B  per-wave [query][key]
  __shared__ float rpsPad[224];          // rpb[head] 13x13 at +16, zero pad

  int tb = blockIdx.x;               // 0..35
  int i0 = (tb/6)*16, j0 = (tb%6)*16;
  int head = blockIdx.y, b = blockIdx.z;
  int tid = threadIdx.x;
  int wave = tid >> 6, lane = tid & 63;
  int lane16 = lane & 15, quad = lane >> 4;

  int hs0 = max(i0-3, 0);
  int ws0 = max(j0-3, 0);
  size_t kvbase = ((size_t)(b*NHEADS + head)) * HWP * HD;

  // ---- stage K halo (chunk-major, gload 16B) : 9 pixel-blocks of 64
  for (int pb = wave; pb < 9; pb += 4){
    int s = pb*64 + lane;                  // halo slot 0..575
    int xx = s >> 3; int r = (xx*171) >> 9; // r = s/24
    int c24 = s - r*24; int cc = min(c24, 21);
    int gr = min(hs0 + r,  HH-1);
    int gc = min(ws0 + cc, WW-1);
    const ushort_t* gp = kb + kvbase + (size_t)(gr*WW + gc)*HD;
    #pragma unroll
    for (int c = 0; c < 4; c++)
      gload_lds16(gp + c*8, &kT[c*(HSLOT*8) + pb*64*8]);
  }
  // ---- stage V halo transposed [ch][pix]
  for (int it = 0; it < 9; it++){
    int idx = it*256 + tid;                // 0..2303
    int pix = idx >> 2, c = idx & 3;
    int xx = pix >> 3; int r = (xx*171) >> 9;
    int c24 = pix - r*24; int cc = min(c24, 21);
    int gr = min(hs0 + r,  HH-1);
    int gc = min(ws0 + cc, WW-1);
    us8 vv = *(const us8*)(vb + kvbase + (size_t)(gr*WW + gc)*HD + c*8);
    #pragma unroll
    for (int e = 0; e < 8; e++) vTT[(c*8+e)*HSLOT + pix] = vv[e];
  }
  if (tid < 224) rpsPad[tid] = (tid >= 16 && tid < 185) ? rpb[head*169 + tid - 16] : 0.f;

  // ---- q prefetch: this wave's 4 query rows, B-frag per row (lane16 = query j)
  s8v qfrag[4];
  #pragma unroll
  for (int rr = 0; rr < 4; rr++){
    int i = i0 + wave*4 + rr;
    qfrag[rr] = *(const s8v*)(qb + kvbase + (size_t)(i*WW + j0 + lane16)*HD + quad*8);
  }

  // ---- per-lane static bias decode table: for reg idx = t*4+r,
  // n = t*16+quad*4+r; pack (col | (rk*13+col)<<8), col=255 if rk>=7 (masked)
  unsigned int pk[22];
  #pragma unroll
  for (int ii = 0; ii < 22; ii++){
    unsigned int w = 0;
    #pragma unroll
    for (int h = 0; h < 2; h++){
      int idx = ii*2 + h;
      int tt = idx >> 2, r = idx & 3;
      int n = tt*16 + quad*4 + r;
      int xx = n >> 3; int rk = (xx*171) >> 9;   // n/24
      int col = n - rk*24;
      int code = (rk >= 7) ? 255 : col;
      int m13c = rk*13 + col;
      w |= (unsigned)((code & 255) | (m13c << 8)) << (h*16);
    }
    pk[ii] = w;
  }

  int j = j0 + lane16;
  int cs_g = min(max(j-3, 0), WW-KS);
  unsigned int cs = (unsigned)(cs_g - ws0);        // window start col, 0..15
  int lanePart = ws0 - j + 6 + 16;                 // +16 = rpsPad offset

  __syncthreads();   // staging visible (drains vmcnt+lgkmcnt)

  #pragma unroll 1
  for (int rr = 0; rr < 4; rr++){
    int i = i0 + wave*4 + rr;
    int si_g = min(max(i-3, 0), HH-KS);
    int si = si_g - hs0;                 // 0..15
    int bi0 = si_g - i + 6;
    int rowBase = bi0*13 + lanePart;
    int kbase = si*HSTR;

    // QK: 11 MFMAs, A = K-tile (m=key), B = q (n=query)
    f4v c[NT];
    #pragma unroll
    for (int tt = 0; tt < NT; tt++){
      s8v af = *(const s8v*)&kT[quad*(HSLOT*8) + (kbase + tt*16 + lane16)*8];
      c[tt] = __builtin_amdgcn_mfma_f32_16x16x32_bf16(af, qfrag[rr], (f4v){0.f,0.f,0.f,0.f}, 0, 0, 0);
    }

    // masked bias + exp + row-sum (query = lane16)
    float s = 0.f;
    #pragma unroll
    for (int tt = 0; tt < NT; tt++){
      #pragma unroll
      for (int r = 0; r < 4; r++){
        int idx = tt*4 + r;
        unsigned int ex = pk[idx >> 1] >> ((idx & 1)*16);
        unsigned int col = ex & 255u;
        int m13c = (int)((ex >> 8) & 255u);
        float bias = rpsPad[rowBase + m13c];
        float e = __expf(c[tt][r] + bias);
        e = ((col - cs) <= 6u) ? e : 0.f;
        s += e;
        c[tt][r] = e;
      }
    }
    s += __shfl_xor(s, 16);
    s += __shfl_xor(s, 32);
    float inv = 1.0f / s;

    // write normalized P (bf16) to per-wave Pbuf[query][key]
    ushort_t* pw = &Pbuf[wave][lane16*PBS];
    #pragma unroll
    for (int tt = 0; tt < NT; tt++){
      uint2 pp;
      pp.x = (unsigned)f2bf(c[tt][0]*inv) | ((unsigned)f2bf(c[tt][1]*inv) << 16);
      pp.y = (unsigned)f2bf(c[tt][2]*inv) | ((unsigned)f2bf(c[tt][3]*inv) << 16);
      *(uint2*)&pw[tt*16 + quad*4] = pp;
    }
    *(uint2*)&pw[NT*16 + quad*4] = (uint2){0u, 0u};   // zero keys 176..191

    // AV: 6 k-steps x 2 ch-tiles; A = P (m=query), B = V^T (n=ch)
    f4v o0 = {0.f,0.f,0.f,0.f}, o1 = {0.f,0.f,0.f,0.f};
    #pragma unroll
    for (int kk = 0; kk < 6; kk++){
      s8v pa = *(const s8v*)&Pbuf[wave][lane16*PBS + kk*32 + quad*8];
      s8v v0 = *(const s8v*)&vTT[lane16*HSLOT      + kbase + kk*32 + quad*8];
      s8v v1 = *(const s8v*)&vTT[(16+lane16)*HSLOT + kbase + kk*32 + quad*8];
      o0 = __builtin_amdgcn_mfma_f32_16x16x32_bf16(pa, v0, o0, 0, 0, 0);
      o1 = __builtin_amdgcn_mfma_f32_16x16x32_bf16(pa, v1, o1, 0, 0, 0);
    }

    // store: D row = query (quad*4+r), col = ch (lane16)
    size_t mb = ((size_t)(b*HWP) + (size_t)i*WW + j0 + quad*4)*CH + head*HD + lane16;
    #pragma unroll
    for (int r = 0; r < 4; r++){
      merged[mb + (size_t)r*CH]      = f2bf(o0[r]);
      merged[mb + (size_t)r*CH + 16] = f2bf(o1[r]);
    }
  }
}

// ---------------------------------------------------------------- kernel 5
__global__ __launch_bounds__(256) void proj_gemm(
    const ushort_t* __restrict__ merged, const ushort_t* __restrict__ wbf,
    const float* __restrict__ bias, float* __restrict__ y)
{
  __shared__ ushort_t As[128*32];
  __shared__ ushort_t Bs[128*32];
  int m0 = blockIdx.x * 128;
  int n0 = blockIdx.y * 128;
  int b  = blockIdx.z;
  int tid = threadIdx.x;
  int wave = tid >> 6, lane = tid & 63;
  const ushort_t* Abase = merged + ((size_t)(b*HWP + m0))*CH;
  const ushort_t* Bbase = wbf + 3*65536 + n0*CH;

  f4v acc[4][4];
  #pragma unroll
  for (int i=0;i<4;i++)
    #pragma unroll
    for (int j=0;j<4;j++) acc[i][j] = (f4v){0.f,0.f,0.f,0.f};

  int wm = wave & 1, wn = wave >> 1;
  int lane16 = lane & 15, quad = lane >> 4;
  int lrow = lane >> 2, lchunk = lane & 3;

  for (int kt = 0; kt < 8; kt++){
    #pragma unroll
    for (int inst = 0; inst < 2; inst++){
      int row0 = wave*32 + inst*16;
      gload_lds16(Abase + (size_t)(row0 + lrow)*CH + kt*32 + lchunk*8, &As[row0*32]);
      gload_lds16(Bbase + (size_t)(row0 + lrow)*CH + kt*32 + lchunk*8, &Bs[row0*32]);
    }
    __syncthreads();
    s8v a[4], bf[4];
    #pragma unroll
    for (int mi=0;mi<4;mi++) a[mi]  = *(const s8v*)&As[(wm*64 + mi*16 + lane16)*32 + quad*8];
    #pragma unroll
    for (int ni=0;ni<4;ni++) bf[ni] = *(const s8v*)&Bs[(wn*64 + ni*16 + lane16)*32 + quad*8];
    #pragma unroll
    for (int mi=0;mi<4;mi++)
      #pragma unroll
      for (int ni=0;ni<4;ni++)
        acc[mi][ni] = __builtin_amdgcn_mfma_f32_16x16x32_bf16(a[mi], bf[ni], acc[mi][ni], 0, 0, 0);
    __syncthreads();
  }

  #pragma unroll
  for (int mi=0;mi<4;mi++){
    #pragma unroll
    for (int ni=0;ni<4;ni++){
      int o = n0 + wn*64 + ni*16 + lane16;
      float bo = bias[o];
      int mb = m0 + wm*64 + mi*16 + quad*4;
      float4 val;
      val.x = acc[mi][ni][0] + bo;
      val.y = acc[mi][ni][1] + bo;
      val.z = acc[mi][ni][2] + bo;
      val.w = acc[mi][ni][3] + bo;
      *(float4*)&y[((size_t)(b*CH + o))*HWP + mb] = val;
    }
  }
}

// ---------------------------------------------------------------- launch
extern "C" void kernel_launch(void* const* d_in, const int* in_sizes, int n_in,
                              void* d_out, int out_size, void* d_ws, size_t ws_size,
                              hipStream_t stream)
{
  const float* x   = (const float*)d_in[0];
  const float* wq  = (const float*)d_in[1];
  const float* wk  = (const float*)d_in[2];
  const float* wv  = (const float*)d_in[3];
  const float* wp  = (const float*)d_in[4];
  const float* bp  = (const float*)d_in[5];
  const float* rpb = (const float*)d_in[6];
  float* y = (float*)d_out;

  const size_t SZ = (size_t)BATCH * HWP * CH * 2;
  char* ws = (char*)d_ws;
  ushort_t* xT     = (ushort_t*)ws;  ws += SZ;
  ushort_t* qbuf   = (ushort_t*)ws;  ws += SZ;
  ushort_t* kbuf   = (ushort_t*)ws;  ws += SZ;
  ushort_t* vbuf   = (ushort_t*)ws;  ws += SZ;
  ushort_t* merged = (ushort_t*)ws;  ws += SZ;
  ushort_t* wbf    = (ushort_t*)ws;  ws += (size_t)4*65536*2;
  if (ws_size < (size_t)5*SZ + 4*65536*2) return;

  wcvt_kernel <<<dim3(1024),        dim3(256), 0, stream>>>(wq, wk, wv, wp, wbf);
  xpose_kernel<<<dim3(144, 8, 8),   dim3(256), 0, stream>>>(x, xT);
  qkv_gemm    <<<dim3(72, 2, 24),   dim3(256), 0, stream>>>(xT, wbf, qbuf, kbuf, vbuf);
  attn_kernel <<<dim3(36, 8, 8),    dim3(256), 0, stream>>>(qbuf, kbuf, vbuf, rpb, merged);
  proj_gemm   <<<dim3(72, 2, 8),    dim3(256), 0, stream>>>(merged, wbf, bp, y);
}

// Round 4
// 311.855 us; speedup vs baseline: 1.2283x; 1.2283x over previous
//
#include <hip/hip_runtime.h>
#include <stdint.h>

// Problem constants
#define BATCH  8
#define CH     256
#define HH     96
#define WW     96
#define NHEADS 8
#define HD     32
#define KS     7
#define HWP    (HH*WW)          // 9216 pixels per image
#define SCALE  0.17677669529663687f   // 1/sqrt(32)

// attention kernel geometry
#define HSTR  24     // halo row stride in pixels
#define HSLOT 576    // staged halo slots (24 rows x 24)
#define VSTR  584    // vTT row stride (ushorts): 584/8=73 odd -> balanced banks
#define NT    11     // QK n-tiles of 16 over 176 padded dense keys
#define PBS   200    // Pbuf row stride (ushorts); 400B: AV b128 reads balanced

typedef unsigned short ushort_t;
typedef unsigned short us8 __attribute__((ext_vector_type(8)));
typedef short s8v __attribute__((ext_vector_type(8)));   // MFMA A/B frag (8 bf16)
typedef float f4v __attribute__((ext_vector_type(4)));   // MFMA C/D frag

__device__ __forceinline__ ushort_t f2bf(float f){
  unsigned int u = __float_as_uint(f);
  u = u + 0x7fffu + ((u >> 16) & 1u);
  return (ushort_t)(u >> 16);
}
__device__ __forceinline__ float bflo(unsigned int u){ return __uint_as_float(u << 16); }

__device__ __forceinline__ void gload_lds16(const void* g, void* l){
  __builtin_amdgcn_global_load_lds(
      (const __attribute__((address_space(1))) void*)g,
      (__attribute__((address_space(3))) void*)l, 16, 0, 0);
}

// ---------------------------------------------------------------- kernel 1
__global__ __launch_bounds__(256) void wcvt_kernel(
    const float* __restrict__ wq, const float* __restrict__ wk,
    const float* __restrict__ wv, const float* __restrict__ wp,
    ushort_t* __restrict__ wbf)
{
  int i = blockIdx.x*256 + threadIdx.x;
  int mat = i >> 16;
  int off = i & 65535;
  const float* src = (mat==0) ? wq : (mat==1) ? wk : (mat==2) ? wv : wp;
  wbf[i] = f2bf(src[off]);
}

// ---------------------------------------------------------------- kernel 2
// x (B,C,H,W) fp32 -> xT (B, HW, C) bf16
__global__ __launch_bounds__(256) void xpose_kernel(
    const float* __restrict__ x, ushort_t* __restrict__ xT)
{
  __shared__ unsigned int tile[32][33];
  int p0 = blockIdx.x * 64;
  int c0 = blockIdx.y * 32;
  int b  = blockIdx.z;
  int tid = threadIdx.x;
  int tx = tid & 31, ty = tid >> 5;
  const float* xb = x + ((size_t)(b*CH + c0))*HWP;
  #pragma unroll
  for (int r = 0; r < 4; r++){
    int c = r*8 + ty;
    float2 v = *(const float2*)(xb + (size_t)c*HWP + p0 + tx*2);
    tile[c][tx] = (unsigned int)f2bf(v.x) | ((unsigned int)f2bf(v.y) << 16);
  }
  __syncthreads();
  int pv = tid >> 2, cq = tid & 3;
  ushort_t tmp[8];
  #pragma unroll
  for (int s = 0; s < 8; s++){
    unsigned int w = tile[cq*8 + s][pv >> 1];
    tmp[s] = (ushort_t)((pv & 1) ? (w >> 16) : (w & 0xffffu));
  }
  *(us8*)(xT + ((size_t)(b*HWP + p0 + pv))*CH + c0 + cq*8) = *(us8*)tmp;
}

// ---------------------------------------------------------------- kernel 3
// QKV GEMM: m97 structure; writes q(prescaled)/k/v as [b][head][pix][hd] bf16
__global__ __launch_bounds__(256) void qkv_gemm(
    const ushort_t* __restrict__ xT, const ushort_t* __restrict__ wbf,
    ushort_t* __restrict__ qb, ushort_t* __restrict__ kb, ushort_t* __restrict__ vb)
{
  __shared__ ushort_t As[128*32];
  __shared__ ushort_t Bs[128*32];
  int m0 = blockIdx.x * 128;
  int n0 = blockIdx.y * 128;
  int b  = blockIdx.z / 3;
  int mat= blockIdx.z % 3;
  int tid = threadIdx.x;
  int wave = tid >> 6, lane = tid & 63;
  const ushort_t* Abase = xT + ((size_t)(b*HWP + m0))*CH;
  const ushort_t* Bbase = wbf + mat*65536 + n0*CH;

  f4v acc[4][4];
  #pragma unroll
  for (int i=0;i<4;i++)
    #pragma unroll
    for (int j=0;j<4;j++) acc[i][j] = (f4v){0.f,0.f,0.f,0.f};

  int wm = wave & 1, wn = wave >> 1;
  int lane16 = lane & 15, quad = lane >> 4;
  int lrow = lane >> 2, lchunk = lane & 3;

  for (int kt = 0; kt < 8; kt++){
    #pragma unroll
    for (int inst = 0; inst < 2; inst++){
      int row0 = wave*32 + inst*16;
      gload_lds16(Abase + (size_t)(row0 + lrow)*CH + kt*32 + lchunk*8, &As[row0*32]);
      gload_lds16(Bbase + (size_t)(row0 + lrow)*CH + kt*32 + lchunk*8, &Bs[row0*32]);
    }
    __syncthreads();
    s8v a[4], bf[4];
    #pragma unroll
    for (int mi=0;mi<4;mi++) a[mi]  = *(const s8v*)&As[(wm*64 + mi*16 + lane16)*32 + quad*8];
    #pragma unroll
    for (int ni=0;ni<4;ni++) bf[ni] = *(const s8v*)&Bs[(wn*64 + ni*16 + lane16)*32 + quad*8];
    #pragma unroll
    for (int mi=0;mi<4;mi++)
      #pragma unroll
      for (int ni=0;ni<4;ni++)
        acc[mi][ni] = __builtin_amdgcn_mfma_f32_16x16x32_bf16(a[mi], bf[ni], acc[mi][ni], 0, 0, 0);
    __syncthreads();
  }

  ushort_t* dst = (mat==0) ? qb : (mat==1) ? kb : vb;
  float sc = (mat==0) ? SCALE : 1.0f;
  size_t obase = (size_t)b * NHEADS * HWP * HD;
  #pragma unroll
  for (int mi=0;mi<4;mi++){
    #pragma unroll
    for (int ni=0;ni<4;ni++){
      int o = n0 + wn*64 + ni*16 + lane16;
      int head = o >> 5, hd = o & 31;
      #pragma unroll
      for (int r=0;r<4;r++){
        int m = m0 + wm*64 + mi*16 + quad*4 + r;
        dst[obase + ((size_t)head*HWP + m)*HD + hd] = f2bf(acc[mi][ni][r] * sc);
      }
    }
  }
}

// ---------------------------------------------------------------- kernel 4
// MFMA neighborhood attention, v2: 512 threads (8 waves), 2 query rows per
// wave interleaved in one branch-free body (ILP), 2 waves/SIMD (TLP).
// Per query-row: QK = 11 mfma (dense 176-key span), masked-bias softmax in
// C-layout (sum = 2 shuffles), P->Pbuf (per-wave, reused across the 2 rows;
// same-wave DS ordering makes the reuse safe), AV = 12 mfma with V staged
// transposed at stride 584 (odd/8 -> balanced LDS banks).
__global__ __launch_bounds__(512) void attn_kernel(
    const ushort_t* __restrict__ qb, const ushort_t* __restrict__ kb,
    const ushort_t* __restrict__ vb, const float* __restrict__ rpb,
    ushort_t* __restrict__ merged)
{
  __shared__ ushort_t kT[4*HSLOT*8];     // 36864 B  [chunk][pix][8]
  __shared__ ushort_t vTT[32*VSTR];      // 37376 B  [ch][pix] stride 584
  __shared__ ushort_t Pbuf[8][16*PBS];   // 51200 B  per-wave [query][key]
  __shared__ float rpsPad[224];          // rpb[head] 13x13 at +16, zero pad

  int tb = blockIdx.x;               // 0..35
  int i0 = (tb/6)*16, j0 = (tb%6)*16;
  int head = blockIdx.y, b = blockIdx.z;
  int tid = threadIdx.x;
  int wave = tid >> 6, lane = tid & 63;
  int lane16 = lane & 15, quad = lane >> 4;

  int hs0 = max(i0-3, 0);
  int ws0 = max(j0-3, 0);
  size_t kvbase = ((size_t)(b*NHEADS + head)) * HWP * HD;

  // ---- stage K halo (chunk-major, gload 16B): 9 pixel-blocks of 64
  for (int pb = wave; pb < 9; pb += 8){
    int s = pb*64 + lane;
    int xx = s >> 3; int r = (xx*171) >> 9;   // r = s/24
    int c24 = s - r*24; int cc = min(c24, 21);
    int gr = min(hs0 + r,  HH-1);
    int gc = min(ws0 + cc, WW-1);
    const ushort_t* gp = kb + kvbase + (size_t)(gr*WW + gc)*HD;
    #pragma unroll
    for (int c = 0; c < 4; c++)
      gload_lds16(gp + c*8, &kT[c*(HSLOT*8) + pb*64*8]);
  }
  // ---- stage V halo transposed [ch][pix], stride VSTR
  #pragma unroll
  for (int it = 0; it < 5; it++){
    int idx = it*512 + tid;                // 0..2303 used
    if (idx < 2304){
      int pix = idx >> 2, c = idx & 3;
      int xx = pix >> 3; int r = (xx*171) >> 9;
      int c24 = pix - r*24; int cc = min(c24, 21);
      int gr = min(hs0 + r,  HH-1);
      int gc = min(ws0 + cc, WW-1);
      us8 vv = *(const us8*)(vb + kvbase + (size_t)(gr*WW + gc)*HD + c*8);
      #pragma unroll
      for (int e = 0; e < 8; e++) vTT[(c*8+e)*VSTR + pix] = vv[e];
    }
  }
  if (tid < 224) rpsPad[tid] = (tid >= 16 && tid < 185) ? rpb[head*169 + tid - 16] : 0.f;

  // ---- q prefetch: this wave's 2 query rows, B-frag per row (lane16 = query col)
  s8v qfragA = *(const s8v*)(qb + kvbase + (size_t)((i0 + wave*2    )*WW + j0 + lane16)*HD + quad*8);
  s8v qfragB = *(const s8v*)(qb + kvbase + (size_t)((i0 + wave*2 + 1)*WW + j0 + lane16)*HD + quad*8);

  // ---- per-lane static bias decode table: for idx = tt*4+r,
  // n = tt*16+quad*4+r; pack (col | (rk*13+col)<<8), col=255 if rk>=7 (masked)
  unsigned int pk[22];
  #pragma unroll
  for (int ii = 0; ii < 22; ii++){
    unsigned int w = 0;
    #pragma unroll
    for (int h = 0; h < 2; h++){
      int idx = ii*2 + h;
      int tt = idx >> 2, r = idx & 3;
      int n = tt*16 + quad*4 + r;
      int xx = n >> 3; int rk = (xx*171) >> 9;   // n/24
      int col = n - rk*24;
      int code = (rk >= 7) ? 255 : col;
      int m13c = rk*13 + col;
      w |= (unsigned)((code & 255) | (m13c << 8)) << (h*16);
    }
    pk[ii] = w;
  }

  int j = j0 + lane16;
  int cs_g = min(max(j-3, 0), WW-KS);
  unsigned int cs = (unsigned)(cs_g - ws0);        // window start col, 0..15
  int lanePart = ws0 - j + 6 + 16;                 // +16 = rpsPad offset

  __syncthreads();   // staging visible (drains vmcnt+lgkmcnt)

  // ---- two query rows, interleaved
  int iA = i0 + wave*2, iB = iA + 1;
  int siA_g = min(max(iA-3, 0), HH-KS);
  int siB_g = min(max(iB-3, 0), HH-KS);
  int rowBaseA = (siA_g - iA + 6)*13 + lanePart;
  int rowBaseB = (siB_g - iB + 6)*13 + lanePart;
  int kbaseA = (siA_g - hs0)*HSTR;
  int kbaseB = (siB_g - hs0)*HSTR;

  // QK both rows: 22 independent MFMAs
  f4v cA[NT], cB[NT];
  #pragma unroll
  for (int tt = 0; tt < NT; tt++){
    s8v af = *(const s8v*)&kT[quad*(HSLOT*8) + (kbaseA + tt*16 + lane16)*8];
    cA[tt] = __builtin_amdgcn_mfma_f32_16x16x32_bf16(af, qfragA, (f4v){0.f,0.f,0.f,0.f}, 0, 0, 0);
  }
  #pragma unroll
  for (int tt = 0; tt < NT; tt++){
    s8v af = *(const s8v*)&kT[quad*(HSLOT*8) + (kbaseB + tt*16 + lane16)*8];
    cB[tt] = __builtin_amdgcn_mfma_f32_16x16x32_bf16(af, qfragB, (f4v){0.f,0.f,0.f,0.f}, 0, 0, 0);
  }

  // softmax both rows (query = lane16; logits tiny -> no max subtraction)
  float sA = 0.f, sB = 0.f;
  #pragma unroll
  for (int tt = 0; tt < NT; tt++){
    #pragma unroll
    for (int r = 0; r < 4; r++){
      int idx = tt*4 + r;
      unsigned int ex = pk[idx >> 1] >> ((idx & 1)*16);
      unsigned int col = ex & 255u;
      int m13c = (int)((ex >> 8) & 255u);
      float eA = __expf(cA[tt][r] + rpsPad[rowBaseA + m13c]);
      float eB = __expf(cB[tt][r] + rpsPad[rowBaseB + m13c]);
      bool valid = ((col - cs) <= 6u);
      eA = valid ? eA : 0.f;
      eB = valid ? eB : 0.f;
      sA += eA; sB += eB;
      cA[tt][r] = eA; cB[tt][r] = eB;
    }
  }
  sA += __shfl_xor(sA, 16); sA += __shfl_xor(sA, 32);
  sB += __shfl_xor(sB, 16); sB += __shfl_xor(sB, 32);
  float invA = 1.0f / sA, invB = 1.0f / sB;

  ushort_t* pw = &Pbuf[wave][lane16*PBS];

  // ---- row A: P write, AV, store
  #pragma unroll
  for (int tt = 0; tt < NT; tt++){
    uint2 pp;
    pp.x = (unsigned)f2bf(cA[tt][0]*invA) | ((unsigned)f2bf(cA[tt][1]*invA) << 16);
    pp.y = (unsigned)f2bf(cA[tt][2]*invA) | ((unsigned)f2bf(cA[tt][3]*invA) << 16);
    *(uint2*)&pw[tt*16 + quad*4] = pp;
  }
  *(uint2*)&pw[NT*16 + quad*4] = (uint2){0u, 0u};   // zero keys 176..191

  f4v o0 = {0.f,0.f,0.f,0.f}, o1 = {0.f,0.f,0.f,0.f};
  #pragma unroll
  for (int kk = 0; kk < 6; kk++){
    s8v pa = *(const s8v*)&Pbuf[wave][lane16*PBS + kk*32 + quad*8];
    s8v v0 = *(const s8v*)&vTT[lane16*VSTR      + kbaseA + kk*32 + quad*8];
    s8v v1 = *(const s8v*)&vTT[(16+lane16)*VSTR + kbaseA + kk*32 + quad*8];
    o0 = __builtin_amdgcn_mfma_f32_16x16x32_bf16(pa, v0, o0, 0, 0, 0);
    o1 = __builtin_amdgcn_mfma_f32_16x16x32_bf16(pa, v1, o1, 0, 0, 0);
  }
  {
    size_t mb = ((size_t)(b*HWP) + (size_t)iA*WW + j0 + quad*4)*CH + head*HD + lane16;
    #pragma unroll
    for (int r = 0; r < 4; r++){
      merged[mb + (size_t)r*CH]      = f2bf(o0[r]);
      merged[mb + (size_t)r*CH + 16] = f2bf(o1[r]);
    }
  }

  // ---- row B: P write (same-wave DS order makes Pbuf reuse safe), AV, store
  #pragma unroll
  for (int tt = 0; tt < NT; tt++){
    uint2 pp;
    pp.x = (unsigned)f2bf(cB[tt][0]*invB) | ((unsigned)f2bf(cB[tt][1]*invB) << 16);
    pp.y = (unsigned)f2bf(cB[tt][2]*invB) | ((unsigned)f2bf(cB[tt][3]*invB) << 16);
    *(uint2*)&pw[tt*16 + quad*4] = pp;
  }
  *(uint2*)&pw[NT*16 + quad*4] = (uint2){0u, 0u};

  f4v p0 = {0.f,0.f,0.f,0.f}, p1 = {0.f,0.f,0.f,0.f};
  #pragma unroll
  for (int kk = 0; kk < 6; kk++){
    s8v pa = *(const s8v*)&Pbuf[wave][lane16*PBS + kk*32 + quad*8];
    s8v v0 = *(const s8v*)&vTT[lane16*VSTR      + kbaseB + kk*32 + quad*8];
    s8v v1 = *(const s8v*)&vTT[(16+lane16)*VSTR + kbaseB + kk*32 + quad*8];
    p0 = __builtin_amdgcn_mfma_f32_16x16x32_bf16(pa, v0, p0, 0, 0, 0);
    p1 = __builtin_amdgcn_mfma_f32_16x16x32_bf16(pa, v1, p1, 0, 0, 0);
  }
  {
    size_t mb = ((size_t)(b*HWP) + (size_t)iB*WW + j0 + quad*4)*CH + head*HD + lane16;
    #pragma unroll
    for (int r = 0; r < 4; r++){
      merged[mb + (size_t)r*CH]      = f2bf(p0[r]);
      merged[mb + (size_t)r*CH + 16] = f2bf(p1[r]);
    }
  }
}

// ---------------------------------------------------------------- kernel 5
__global__ __launch_bounds__(256) void proj_gemm(
    const ushort_t* __restrict__ merged, const ushort_t* __restrict__ wbf,
    const float* __restrict__ bias, float* __restrict__ y)
{
  __shared__ ushort_t As[128*32];
  __shared__ ushort_t Bs[128*32];
  int m0 = blockIdx.x * 128;
  int n0 = blockIdx.y * 128;
  int b  = blockIdx.z;
  int tid = threadIdx.x;
  int wave = tid >> 6, lane = tid & 63;
  const ushort_t* Abase = merged + ((size_t)(b*HWP + m0))*CH;
  const ushort_t* Bbase = wbf + 3*65536 + n0*CH;

  f4v acc[4][4];
  #pragma unroll
  for (int i=0;i<4;i++)
    #pragma unroll
    for (int j=0;j<4;j++) acc[i][j] = (f4v){0.f,0.f,0.f,0.f};

  int wm = wave & 1, wn = wave >> 1;
  int lane16 = lane & 15, quad = lane >> 4;
  int lrow = lane >> 2, lchunk = lane & 3;

  for (int kt = 0; kt < 8; kt++){
    #pragma unroll
    for (int inst = 0; inst < 2; inst++){
      int row0 = wave*32 + inst*16;
      gload_lds16(Abase + (size_t)(row0 + lrow)*CH + kt*32 + lchunk*8, &As[row0*32]);
      gload_lds16(Bbase + (size_t)(row0 + lrow)*CH + kt*32 + lchunk*8, &Bs[row0*32]);
    }
    __syncthreads();
    s8v a[4], bf[4];
    #pragma unroll
    for (int mi=0;mi<4;mi++) a[mi]  = *(const s8v*)&As[(wm*64 + mi*16 + lane16)*32 + quad*8];
    #pragma unroll
    for (int ni=0;ni<4;ni++) bf[ni] = *(const s8v*)&Bs[(wn*64 + ni*16 + lane16)*32 + quad*8];
    #pragma unroll
    for (int mi=0;mi<4;mi++)
      #pragma unroll
      for (int ni=0;ni<4;ni++)
        acc[mi][ni] = __builtin_amdgcn_mfma_f32_16x16x32_bf16(a[mi], bf[ni], acc[mi][ni], 0, 0, 0);
    __syncthreads();
  }

  #pragma unroll
  for (int mi=0;mi<4;mi++){
    #pragma unroll
    for (int ni=0;ni<4;ni++){
      int o = n0 + wn*64 + ni*16 + lane16;
      float bo = bias[o];
      int mb = m0 + wm*64 + mi*16 + quad*4;
      float4 val;
      val.x = acc[mi][ni][0] + bo;
      val.y = acc[mi][ni][1] + bo;
      val.z = acc[mi][ni][2] + bo;
      val.w = acc[mi][ni][3] + bo;
      *(float4*)&y[((size_t)(b*CH + o))*HWP + mb] = val;
    }
  }
}

// ---------------------------------------------------------------- launch
extern "C" void kernel_launch(void* const* d_in, const int* in_sizes, int n_in,
                              void* d_out, int out_size, void* d_ws, size_t ws_size,
                              hipStream_t stream)
{
  const float* x   = (const float*)d_in[0];
  const float* wq  = (const float*)d_in[1];
  const float* wk  = (const float*)d_in[2];
  const float* wv  = (const float*)d_in[3];
  const float* wp  = (const float*)d_in[4];
  const float* bp  = (const float*)d_in[5];
  const float* rpb = (const float*)d_in[6];
  float* y = (float*)d_out;

  const size_t SZ = (size_t)BATCH * HWP * CH * 2;
  char* ws = (char*)d_ws;
  ushort_t* xT     = (ushort_t*)ws;  ws += SZ;
  ushort_t* qbuf   = (ushort_t*)ws;  ws += SZ;
  ushort_t* kbuf   = (ushort_t*)ws;  ws += SZ;
  ushort_t* vbuf   = (ushort_t*)ws;  ws += SZ;
  ushort_t* merged = (ushort_t*)ws;  ws += SZ;
  ushort_t* wbf    = (ushort_t*)ws;  ws += (size_t)4*65536*2;
  if (ws_size < (size_t)5*SZ + 4*65536*2) return;

  wcvt_kernel <<<dim3(1024),        dim3(256), 0, stream>>>(wq, wk, wv, wp, wbf);
  xpose_kernel<<<dim3(144, 8, 8),   dim3(256), 0, stream>>>(x, xT);
  qkv_gemm    <<<dim3(72, 2, 24),   dim3(256), 0, stream>>>(xT, wbf, qbuf, kbuf, vbuf);
  attn_kernel <<<dim3(36, 8, 8),    dim3(512), 0, stream>>>(qbuf, kbuf, vbuf, rpb, merged);
  proj_gemm   <<<dim3(72, 2, 8),    dim3(256), 0, stream>>>(merged, wbf, bp, y);
}